// Round 1
// baseline (3031.261 us; speedup 1.0000x reference)
//
#include <hip/hip_runtime.h>
#include <hip/hip_cooperative_groups.h>
#include <math.h>

namespace cg = cooperative_groups;

#define N_NODES 8192
#define DIM     512
#define KTOT    1024   // 512 (x) + 512 (h)
#define NCOLS   4096   // 8 quantities * 512 dims, interleaved: col = 8*d + q
#define MT 64
#define NT 64
#define KC 16

__device__ __forceinline__ float sigm(float x) { return 1.0f / (1.0f + expf(-x)); }

// ---------------------------------------------------------------------------
// Prep: build combined interleaved weight matrix Wcomb [KTOT][NCOLS]
// rows 0..511   = x-side weights, rows 512..1023 = h-side weights
// col j = 8*d + q ; q in {0:i_v,1:o_v,2:u_v,3:f_v,4:i_l,5:o_l,6:u_l,7:f_l}
// ---------------------------------------------------------------------------
__global__ void prep_weights_kernel(
    const float* __restrict__ Wx_iou_v, const float* __restrict__ Wh_iou_v,
    const float* __restrict__ Wx_f_v,   const float* __restrict__ Wh_f_v,
    const float* __restrict__ Wx_iou_l, const float* __restrict__ Wh_iou_l,
    const float* __restrict__ Wx_f_l,   const float* __restrict__ Wh_f_l,
    float* __restrict__ Wcomb)
{
    int gid = blockIdx.x * blockDim.x + threadIdx.x;
    if (gid >= KTOT * NCOLS) return;
    int k = gid >> 12;            // row in combined K (0..1023)
    int j = gid & (NCOLS - 1);    // interleaved col
    int d = j >> 3, q = j & 7;
    int qq = q & 3;
    bool lang = (q & 4) != 0;
    const float* Wx; const float* Wh; int col, stride;
    if (qq < 3) { col = qq * DIM + d; stride = 3 * DIM;
                  Wx = lang ? Wx_iou_l : Wx_iou_v; Wh = lang ? Wh_iou_l : Wh_iou_v; }
    else        { col = d;            stride = DIM;
                  Wx = lang ? Wx_f_l  : Wx_f_v;   Wh = lang ? Wh_f_l  : Wh_f_v; }
    float v = (k < DIM) ? Wx[k * stride + col] : Wh[(k - DIM) * stride + col];
    Wcomb[gid] = v;
}

__global__ void prep_bias_kernel(
    const float* __restrict__ bx_iou_v, const float* __restrict__ bh_iou_v,
    const float* __restrict__ bx_f_v,   const float* __restrict__ bh_f_v,
    const float* __restrict__ bx_iou_l, const float* __restrict__ bh_iou_l,
    const float* __restrict__ bx_f_l,   const float* __restrict__ bh_f_l,
    float* __restrict__ bias)
{
    int j = blockIdx.x * blockDim.x + threadIdx.x;
    if (j >= NCOLS) return;
    int d = j >> 3, q = j & 7;
    int qq = q & 3;
    bool lang = (q & 4) != 0;
    const float* bx; const float* bh; int col;
    if (qq < 3) { col = qq * DIM + d; bx = lang ? bx_iou_l : bx_iou_v; bh = lang ? bh_iou_l : bh_iou_v; }
    else        { col = d;            bx = lang ? bx_f_l  : bx_f_v;   bh = lang ? bh_f_l  : bh_f_v; }
    bias[j] = bx[col] + bh[col];
}

// ---------------------------------------------------------------------------
// Level computation + counting sort (single block, levels live in LDS)
// ---------------------------------------------------------------------------
__global__ void __launch_bounds__(1024) levels_sort_kernel(
    const int* __restrict__ parent,
    int* __restrict__ order, int* __restrict__ offsets,
    int* __restrict__ counts, int* __restrict__ cursors, int* __restrict__ nlev)
{
    __shared__ int s_level[N_NODES];
    __shared__ int s_assigned;
    __shared__ int s_maxlev;
    int tid = threadIdx.x;
    int pr[8];
#pragma unroll
    for (int ii = 0; ii < 8; ++ii) {
        int i = tid + ii * 1024;
        pr[ii] = parent[i];
        s_level[i] = -1;
    }
    for (int i = tid; i <= N_NODES; i += 1024) counts[i] = 0;
    if (tid == 0) { s_assigned = 0; s_maxlev = 0; }
    __syncthreads();

    for (int pass = 0; pass <= N_NODES; ++pass) {
        int newly = 0;
#pragma unroll
        for (int ii = 0; ii < 8; ++ii) {
            int i = tid + ii * 1024;
            if (s_level[i] < 0) {
                int p = pr[ii];
                if (p == 0) { s_level[i] = 0; newly++; }
                else { int lp = s_level[p - 1]; if (lp >= 0) { s_level[i] = lp + 1; newly++; } }
            }
        }
        if (newly) atomicAdd(&s_assigned, newly);
        __syncthreads();
        int a = s_assigned;
        if (a >= N_NODES) break;     // uniform: no writes between barrier and read
        __syncthreads();
    }

    // histogram
#pragma unroll
    for (int ii = 0; ii < 8; ++ii) {
        int i = tid + ii * 1024;
        int lv = s_level[i];
        atomicAdd(&counts[lv], 1);
        atomicMax(&s_maxlev, lv);
    }
    __syncthreads();
    if (tid == 0) {
        int nl = s_maxlev + 1;
        nlev[0] = nl;
        int off = 0;
        for (int l = 0; l < nl; ++l) { offsets[l] = off; cursors[l] = off; off += counts[l]; }
        offsets[nl] = off;  // == N_NODES
    }
    __syncthreads();
    // scatter
#pragma unroll
    for (int ii = 0; ii < 8; ++ii) {
        int i = tid + ii * 1024;
        int pos = atomicAdd(&cursors[s_level[i]], 1);
        order[pos] = i;
    }
}

// ---------------------------------------------------------------------------
// Cooperative kernel: per level, fused GEMM  pre = [x_n | h_p] @ Wcomb + bias
// + LSTM cell epilogue. out = [c (N x 512) | h (N x 512)]
// ---------------------------------------------------------------------------
__global__ void __launch_bounds__(256, 2) tree_cell_kernel(
    const float* __restrict__ inputs, const float* __restrict__ type_mask,
    const float* __restrict__ Wcomb,  const float* __restrict__ bias,
    const int* __restrict__ order,    const int* __restrict__ offsets,
    const int* __restrict__ nlev,     const int* __restrict__ parent,
    float* __restrict__ out)
{
    cg::grid_group grid = cg::this_grid();
    float* cOut = out;
    float* hOut = out + (size_t)N_NODES * DIM;

    __shared__ float As[KC][MT + 4];
    __shared__ float Bs[KC][NT];
    __shared__ int   s_node[MT];
    __shared__ int   s_par[MT];
    __shared__ float s_tm[MT][2];

    int tid = threadIdx.x;
    int tx = tid & 15, ty = tid >> 4;
    bool isLang = (tx & 1) != 0;
    int nl = nlev[0];

    for (int lev = 0; lev < nl; ++lev) {
        int start = offsets[lev];
        int cnt = offsets[lev + 1] - start;
        int mtiles = (cnt + MT - 1) / MT;
        int tiles = mtiles * (NCOLS / NT);

        for (int t = blockIdx.x; t < tiles; t += gridDim.x) {
            int mt = t % mtiles;
            int ntile = t / mtiles;
            int jc = ntile * NT;
            int r0 = mt * MT;

            __syncthreads();   // protect LDS reuse across tile iterations
            if (tid < MT) {
                int r = r0 + tid;
                int node = (r < cnt) ? order[start + r] : -1;
                s_node[tid] = node;
                s_par[tid] = (node >= 0) ? parent[node] : 0;
                float t0 = 0.f, t1 = 0.f;
                if (node >= 0) { t0 = type_mask[node * 2]; t1 = type_mask[node * 2 + 1]; }
                s_tm[tid][0] = t0; s_tm[tid][1] = t1;
            }
            __syncthreads();

            float acc[4][4] = {};
            for (int kc = 0; kc < KTOT / KC; ++kc) {
                int k0 = kc * KC;
                // load A tile (gathered [x_n | h_p]) : thread -> m = tid/4, kk0 = (tid&3)*4
                {
                    int m = tid >> 2;
                    int kk0 = (tid & 3) * 4;
                    int k = k0 + kk0;
                    float4 v = make_float4(0.f, 0.f, 0.f, 0.f);
                    int node = s_node[m];
                    if (node >= 0) {
                        if (k < DIM) {
                            v = *reinterpret_cast<const float4*>(inputs + (size_t)node * DIM + k);
                        } else {
                            int p = s_par[m];
                            if (p > 0)
                                v = *reinterpret_cast<const float4*>(hOut + (size_t)(p - 1) * DIM + (k - DIM));
                        }
                    }
                    As[kk0 + 0][m] = v.x; As[kk0 + 1][m] = v.y;
                    As[kk0 + 2][m] = v.z; As[kk0 + 3][m] = v.w;
                }
                // load B tile
                {
                    int n0 = (tid & 15) * 4;
                    int kk = tid >> 4;
                    float4 v = *reinterpret_cast<const float4*>(Wcomb + (size_t)(k0 + kk) * NCOLS + jc + n0);
                    *reinterpret_cast<float4*>(&Bs[kk][n0]) = v;
                }
                __syncthreads();
#pragma unroll
                for (int kk = 0; kk < KC; ++kk) {
                    float4 a = *reinterpret_cast<const float4*>(&As[kk][ty * 4]);
                    float4 b = *reinterpret_cast<const float4*>(&Bs[kk][tx * 4]);
                    float am[4] = { a.x, a.y, a.z, a.w };
                    float bn[4] = { b.x, b.y, b.z, b.w };
#pragma unroll
                    for (int mi = 0; mi < 4; ++mi)
#pragma unroll
                        for (int ni = 0; ni < 4; ++ni)
                            acc[mi][ni] += am[mi] * bn[ni];
                }
                __syncthreads();
            }

            // epilogue: thread's 4 cols are (i,o,u,f) of one branch of dim d
            int d = (jc + tx * 4) >> 3;
            float b0 = bias[jc + tx * 4 + 0];
            float b1 = bias[jc + tx * 4 + 1];
            float b2 = bias[jc + tx * 4 + 2];
            float b3 = bias[jc + tx * 4 + 3];
#pragma unroll
            for (int mi = 0; mi < 4; ++mi) {
                int lm = ty * 4 + mi;
                int r = r0 + lm;
                if (r < cnt) {
                    int node = s_node[lm];
                    int p = s_par[lm];
                    float cp = (p > 0) ? cOut[(size_t)(p - 1) * DIM + d] : 0.0f;
                    float vi = acc[mi][0] + b0;
                    float vo = acc[mi][1] + b1;
                    float vu = acc[mi][2] + b2;
                    float vf = acc[mi][3] + b3;
                    float cb = sigm(vi) * tanhf(vu) + sigm(vf) * cp;
                    float hb = sigm(vo) * tanhf(cb);
                    float co = __shfl_xor(cb, 1);
                    float ho = __shfl_xor(hb, 1);
                    float tm0 = s_tm[lm][0], tm1 = s_tm[lm][1];
                    float cv = isLang ? co : cb, cl = isLang ? cb : co;
                    float hv = isLang ? ho : hb, hl = isLang ? hb : ho;
                    if (!isLang) {
                        cOut[(size_t)node * DIM + d] = tm0 * cl + tm1 * cv;
                        hOut[(size_t)node * DIM + d] = tm0 * hl + tm1 * hv;
                    }
                }
            }
        }
        grid.sync();
    }
}

// ---------------------------------------------------------------------------
extern "C" void kernel_launch(void* const* d_in, const int* in_sizes, int n_in,
                              void* d_out, int out_size, void* d_ws, size_t ws_size,
                              hipStream_t stream) {
    const float* inputs      = (const float*)d_in[0];
    const float* type_mask   = (const float*)d_in[1];
    const int*   parent      = (const int*)d_in[2];
    const float* W_ioux_vis  = (const float*)d_in[3];
    const float* b_ioux_vis  = (const float*)d_in[4];
    const float* W_iouh_vis  = (const float*)d_in[5];
    const float* b_iouh_vis  = (const float*)d_in[6];
    const float* W_fx_vis    = (const float*)d_in[7];
    const float* b_fx_vis    = (const float*)d_in[8];
    const float* W_fh_vis    = (const float*)d_in[9];
    const float* b_fh_vis    = (const float*)d_in[10];
    const float* W_ioux_lang = (const float*)d_in[11];
    const float* b_ioux_lang = (const float*)d_in[12];
    const float* W_iouh_lang = (const float*)d_in[13];
    const float* b_iouh_lang = (const float*)d_in[14];
    const float* W_fx_lang   = (const float*)d_in[15];
    const float* b_fx_lang   = (const float*)d_in[16];
    const float* W_fh_lang   = (const float*)d_in[17];
    const float* b_fh_lang   = (const float*)d_in[18];

    float* Wcomb  = (float*)d_ws;
    float* bias   = Wcomb + (size_t)KTOT * NCOLS;
    int* order    = (int*)(bias + NCOLS);
    int* offsets  = order + N_NODES;
    int* counts   = offsets + (N_NODES + 1);
    int* cursors  = counts + (N_NODES + 1);
    int* nlev     = cursors + (N_NODES + 1);

    float* out = (float*)d_out;

    hipLaunchKernelGGL(prep_weights_kernel, dim3((KTOT * NCOLS) / 256), dim3(256), 0, stream,
                       W_ioux_vis, W_iouh_vis, W_fx_vis, W_fh_vis,
                       W_ioux_lang, W_iouh_lang, W_fx_lang, W_fh_lang, Wcomb);
    hipLaunchKernelGGL(prep_bias_kernel, dim3(NCOLS / 256), dim3(256), 0, stream,
                       b_ioux_vis, b_iouh_vis, b_fx_vis, b_fh_vis,
                       b_ioux_lang, b_iouh_lang, b_fx_lang, b_fh_lang, bias);
    hipLaunchKernelGGL(levels_sort_kernel, dim3(1), dim3(1024), 0, stream,
                       parent, order, offsets, counts, cursors, nlev);

    int occ = 0;
    if (hipOccupancyMaxActiveBlocksPerMultiprocessor(&occ, (const void*)tree_cell_kernel, 256, 0) != hipSuccess || occ < 1)
        occ = 1;
    int blocksPerCU = occ < 2 ? occ : 2;
    dim3 grid(256 * blocksPerCU);

    void* args[] = { (void*)&inputs, (void*)&type_mask, (void*)&Wcomb, (void*)&bias,
                     (void*)&order, (void*)&offsets, (void*)&nlev, (void*)&parent, (void*)&out };
    hipLaunchCooperativeKernel((const void*)tree_cell_kernel, grid, dim3(256), args, 0, stream);
}

// Round 2
// 1482.908 us; speedup vs baseline: 2.0441x; 2.0441x over previous
//
#include <hip/hip_runtime.h>
#include <hip/hip_cooperative_groups.h>
#include <math.h>

namespace cg = cooperative_groups;

typedef unsigned short ushort_t;
typedef unsigned int uint_t;
typedef __attribute__((ext_vector_type(8))) short short8;
typedef __attribute__((ext_vector_type(4))) float f32x4;

#define N_NODES 8192
#define DIM 512
#define KTOT 1024
#define NCOLS 4096
#define BM 128
#define BN 128
#define BK 32
#define NTILE (NCOLS / BN)   // 32 column tiles
#define KIT (KTOT / BK)      // 32 k iterations
// Wimg: per (ntile, kit) a 16KB LDS-image tile: [plane(2)][col(128)][granule-swizzled 32 k]
#define WIMG_USHORTS ((size_t)NTILE * KIT * 8192)

__device__ __forceinline__ float sigm(float x) { return 1.0f / (1.0f + __expf(-x)); }
__device__ __forceinline__ float tanh_fast(float x) {
    float ax = fabsf(x);
    float e = __expf(2.0f * ax);
    float t = 1.0f - 2.0f / (e + 1.0f);
    return copysignf(t, x);
}

// ---------------------------------------------------------------------------
// Prep: weights -> split bf16 (hi+lo) LDS-image layout.
// Combined W[k][j]: k in [0,1024): 0-511 x-side, 512-1023 h-side.
// j = 8*d + q ; q in {0:i_v,1:o_v,2:u_v,3:f_v,4:i_l,5:o_l,6:u_l,7:f_l}
// Image tile (p=ntile, it): ushort idx = plane*4096 + col*32 + gp*8 + b
//   where gp = gd ^ (col&3), k = it*32 + gd*8 + b, j = p*128 + col.
// ---------------------------------------------------------------------------
__global__ void __launch_bounds__(256) prep_wimg_kernel(
    const float* __restrict__ Wx_iou_v, const float* __restrict__ Wh_iou_v,
    const float* __restrict__ Wx_f_v,   const float* __restrict__ Wh_f_v,
    const float* __restrict__ Wx_iou_l, const float* __restrict__ Wh_iou_l,
    const float* __restrict__ Wx_f_l,   const float* __restrict__ Wh_f_l,
    ushort_t* __restrict__ Wimg)
{
    __shared__ float T[32][132];   // T[kk][jloc]
    int p = blockIdx.x >> 5, it = blockIdx.x & 31;
    int tid = threadIdx.x;
#pragma unroll
    for (int e = 0; e < 16; ++e) {
        int lin = e * 256 + tid;
        int dloc = lin & 15, kk = (lin >> 4) & 31, q = lin >> 9;
        int d = p * 16 + dloc;
        int qq = q & 3; bool lang = q >= 4;
        int k = it * 32 + kk;
        const float* W; int col, stride;
        if (qq < 3) { col = qq * DIM + d; stride = 3 * DIM;
            W = (k < DIM) ? (lang ? Wx_iou_l : Wx_iou_v) : (lang ? Wh_iou_l : Wh_iou_v); }
        else        { col = d; stride = DIM;
            W = (k < DIM) ? (lang ? Wx_f_l : Wx_f_v) : (lang ? Wh_f_l : Wh_f_v); }
        int kr = (k < DIM) ? k : (k - DIM);
        T[kk][dloc * 8 + q] = W[(size_t)kr * stride + col];
    }
    __syncthreads();
    size_t tilebase = (size_t)blockIdx.x * 8192;
#pragma unroll
    for (int gch = 0; gch < 4; ++gch) {
        int gi = gch * 256 + tid;
        int plane = gi >> 9, col = (gi >> 2) & 127, gp = gi & 3;
        int gd = gp ^ (col & 3);
        uint_t wds[4];
#pragma unroll
        for (int i = 0; i < 4; ++i) {
            float f0 = T[gd * 8 + 2 * i][col];
            float f1 = T[gd * 8 + 2 * i + 1][col];
            uint_t u0 = __float_as_uint(f0), u1 = __float_as_uint(f1);
            uint_t h0 = u0 & 0xffff0000u, h1 = u1 & 0xffff0000u;
            uint_t v0, v1;
            if (plane == 0) { v0 = h0 >> 16; v1 = h1; }
            else {
                float r0 = f0 - __uint_as_float(h0), r1 = f1 - __uint_as_float(h1);
                v0 = __float_as_uint(r0) >> 16; v1 = __float_as_uint(r1) & 0xffff0000u;
            }
            wds[i] = v1 | v0;
        }
        *(uint4*)(Wimg + tilebase + (size_t)gi * 8) = make_uint4(wds[0], wds[1], wds[2], wds[3]);
    }
}

__global__ void prep_bias_kernel(
    const float* __restrict__ bx_iou_v, const float* __restrict__ bh_iou_v,
    const float* __restrict__ bx_f_v,   const float* __restrict__ bh_f_v,
    const float* __restrict__ bx_iou_l, const float* __restrict__ bh_iou_l,
    const float* __restrict__ bx_f_l,   const float* __restrict__ bh_f_l,
    float* __restrict__ bias)
{
    int j = blockIdx.x * blockDim.x + threadIdx.x;
    if (j >= NCOLS) return;
    int d = j >> 3, q = j & 7;
    int qq = q & 3;
    bool lang = (q & 4) != 0;
    const float* bx; const float* bh; int col;
    if (qq < 3) { col = qq * DIM + d; bx = lang ? bx_iou_l : bx_iou_v; bh = lang ? bh_iou_l : bh_iou_v; }
    else        { col = d;            bx = lang ? bx_f_l  : bx_f_v;   bh = lang ? bh_f_l  : bh_f_v; }
    bias[j] = bx[col] + bh[col];
}

// ---------------------------------------------------------------------------
// Level computation + counting sort (single block, levels in LDS)
// ---------------------------------------------------------------------------
__global__ void __launch_bounds__(1024) levels_sort_kernel(
    const int* __restrict__ parent,
    int* __restrict__ order, int* __restrict__ offsets,
    int* __restrict__ counts, int* __restrict__ cursors, int* __restrict__ nlev)
{
    __shared__ int s_level[N_NODES];
    __shared__ int s_assigned;
    __shared__ int s_maxlev;
    int tid = threadIdx.x;
    int pr[8];
#pragma unroll
    for (int ii = 0; ii < 8; ++ii) {
        int i = tid + ii * 1024;
        pr[ii] = parent[i];
        s_level[i] = -1;
    }
    for (int i = tid; i <= N_NODES; i += 1024) counts[i] = 0;
    if (tid == 0) { s_assigned = 0; s_maxlev = 0; }
    __syncthreads();

    for (int pass = 0; pass <= N_NODES; ++pass) {
        int newly = 0;
#pragma unroll
        for (int ii = 0; ii < 8; ++ii) {
            int i = tid + ii * 1024;
            if (s_level[i] < 0) {
                int p = pr[ii];
                if (p == 0) { s_level[i] = 0; newly++; }
                else { int lp = s_level[p - 1]; if (lp >= 0) { s_level[i] = lp + 1; newly++; } }
            }
        }
        if (newly) atomicAdd(&s_assigned, newly);
        __syncthreads();
        int a = s_assigned;
        if (a >= N_NODES) break;
        __syncthreads();
    }

#pragma unroll
    for (int ii = 0; ii < 8; ++ii) {
        int i = tid + ii * 1024;
        int lv = s_level[i];
        atomicAdd(&counts[lv], 1);
        atomicMax(&s_maxlev, lv);
    }
    __syncthreads();
    if (tid == 0) {
        int nl = s_maxlev + 1;
        nlev[0] = nl;
        int off = 0;
        for (int l = 0; l < nl; ++l) { offsets[l] = off; cursors[l] = off; off += counts[l]; }
        offsets[nl] = off;
    }
    __syncthreads();
#pragma unroll
    for (int ii = 0; ii < 8; ++ii) {
        int i = tid + ii * 1024;
        int pos = atomicAdd(&cursors[s_level[i]], 1);
        order[pos] = i;
    }
}

// ---------------------------------------------------------------------------
// Staging helpers for the MFMA kernel
// ---------------------------------------------------------------------------
__device__ __forceinline__ void loadA_regs(int it, int tid,
    const int* s_node, const int* s_par,
    const float* __restrict__ inputs, const float* __restrict__ hOut, float* f)
{
    int row = tid >> 1, h16 = tid & 1;
    int node = s_node[row], p = s_par[row];
    bool xside = it < 16;
    bool valid = (node >= 0) && (xside || p > 0);
#pragma unroll
    for (int i = 0; i < 16; ++i) f[i] = 0.f;
    if (valid) {
        const float* base = xside ? (inputs + (size_t)node * DIM + it * 32 + h16 * 16)
                                  : (hOut + (size_t)(p - 1) * DIM + (it - 16) * 32 + h16 * 16);
#pragma unroll
        for (int q4 = 0; q4 < 4; ++q4) {
            float4 v = *(const float4*)(base + q4 * 4);
            f[q4 * 4 + 0] = v.x; f[q4 * 4 + 1] = v.y; f[q4 * 4 + 2] = v.z; f[q4 * 4 + 3] = v.w;
        }
    }
}

__device__ __forceinline__ void writeA_lds(int tid, ushort_t* Ab, const float* f)
{
    int row = tid >> 1, h16 = tid & 1;
    uint_t hw[8], lw[8];
#pragma unroll
    for (int i = 0; i < 8; ++i) {
        float f0 = f[2 * i], f1 = f[2 * i + 1];
        uint_t u0 = __float_as_uint(f0), u1 = __float_as_uint(f1);
        uint_t h0 = u0 & 0xffff0000u, h1 = u1 & 0xffff0000u;
        float r0 = f0 - __uint_as_float(h0), r1 = f1 - __uint_as_float(h1);
        hw[i] = h1 | (h0 >> 16);
        lw[i] = (__float_as_uint(r1) & 0xffff0000u) | (__float_as_uint(r0) >> 16);
    }
    int gd0 = h16 * 2, gd1 = gd0 + 1, rs = row & 3;
    ushort_t* base = Ab + row * 32;
    *(uint4*)(base + (gd0 ^ rs) * 8)        = make_uint4(hw[0], hw[1], hw[2], hw[3]);
    *(uint4*)(base + (gd1 ^ rs) * 8)        = make_uint4(hw[4], hw[5], hw[6], hw[7]);
    *(uint4*)(base + 4096 + (gd0 ^ rs) * 8) = make_uint4(lw[0], lw[1], lw[2], lw[3]);
    *(uint4*)(base + 4096 + (gd1 ^ rs) * 8) = make_uint4(lw[4], lw[5], lw[6], lw[7]);
}

__device__ __forceinline__ void loadB_regs(int it, int ntile, int tid,
                                           const ushort_t* __restrict__ Wimg, uint4* br)
{
    const uint4* g = (const uint4*)(Wimg + ((size_t)(ntile * KIT + it)) * 8192);
#pragma unroll
    for (int j = 0; j < 4; ++j) br[j] = g[(size_t)tid + 256 * j];
}

__device__ __forceinline__ void writeB_lds(int tid, ushort_t* Bb, const uint4* br)
{
    uint4* d = (uint4*)Bb;
#pragma unroll
    for (int j = 0; j < 4; ++j) d[tid + 256 * j] = br[j];
}

__device__ __forceinline__ void mfma_phase(const ushort_t* Ab, const ushort_t* Bb,
                                           int wr, int wc, int lane, f32x4 acc[4][4])
{
    int l15 = lane & 15, g = lane >> 4;
    short8 ah[4], al[4];
#pragma unroll
    for (int m = 0; m < 4; ++m) {
        int row = wr * 64 + m * 16 + l15;
        const ushort_t* pa = Ab + row * 32 + ((g ^ (row & 3)) * 8);
        ah[m] = *(const short8*)pa;
        al[m] = *(const short8*)(pa + 4096);
    }
#pragma unroll
    for (int n = 0; n < 4; ++n) {
        int col = wc * 64 + n * 16 + l15;
        const ushort_t* pb = Bb + col * 32 + ((g ^ (col & 3)) * 8);
        short8 bh = *(const short8*)pb;
        short8 bl = *(const short8*)(pb + 4096);
#pragma unroll
        for (int m = 0; m < 4; ++m) {
            acc[m][n] = __builtin_amdgcn_mfma_f32_16x16x32_bf16(ah[m], bh, acc[m][n], 0, 0, 0);
            acc[m][n] = __builtin_amdgcn_mfma_f32_16x16x32_bf16(al[m], bh, acc[m][n], 0, 0, 0);
            acc[m][n] = __builtin_amdgcn_mfma_f32_16x16x32_bf16(ah[m], bl, acc[m][n], 0, 0, 0);
        }
    }
}

// ---------------------------------------------------------------------------
// Cooperative kernel: per level, split-bf16 MFMA GEMM + LSTM epilogue
// ---------------------------------------------------------------------------
__global__ void __launch_bounds__(256, 2) tree_mfma_kernel(
    const float* __restrict__ inputs, const float* __restrict__ type_mask,
    const ushort_t* __restrict__ Wimg, const float* __restrict__ bias,
    const int* __restrict__ order, const int* __restrict__ offsets,
    const int* __restrict__ nlev, const int* __restrict__ parent,
    float* __restrict__ out)
{
    cg::grid_group grid = cg::this_grid();
    float* cOut = out;
    float* hOut = out + (size_t)N_NODES * DIM;

    __shared__ __align__(16) ushort_t sm16[32768];   // 64KB: A[2 bufs]16KB each? A buf=16KB hi+lo; B buf=16KB
    __shared__ int s_node[BM];
    __shared__ int s_par[BM];
    __shared__ float s_tm[BM][2];

    int tid = threadIdx.x;
    int lane = tid & 63, w = tid >> 6, wr = w >> 1, wc = w & 1;
    int nl = nlev[0];

    for (int lev = 0; lev < nl; ++lev) {
        int start = offsets[lev];
        int cnt = offsets[lev + 1] - start;
        int mtiles = (cnt + BM - 1) / BM;
        int tiles = mtiles * NTILE;

        for (int t = blockIdx.x; t < tiles; t += gridDim.x) {
            int ntile = t % NTILE;
            int mt = t / NTILE;
            int jc = ntile * BN;
            int r0 = mt * BM;

            if (tid < BM) {
                int r = r0 + tid;
                int node = (r < cnt) ? order[start + r] : -1;
                s_node[tid] = node;
                int p = (node >= 0) ? parent[node] : 0;
                s_par[tid] = p;
                float t0 = 0.f, t1 = 0.f;
                if (node >= 0) { t0 = type_mask[node * 2]; t1 = type_mask[node * 2 + 1]; }
                s_tm[tid][0] = t0; s_tm[tid][1] = t1;
            }
            __syncthreads();

            f32x4 acc[4][4];
#pragma unroll
            for (int m = 0; m < 4; ++m)
#pragma unroll
                for (int n = 0; n < 4; ++n) acc[m][n] = (f32x4)(0.f);

            // prologue: stage it=0 into buf 0
            {
                float fA[16]; uint4 br[4];
                loadA_regs(0, tid, s_node, s_par, inputs, hOut, fA);
                loadB_regs(0, ntile, tid, Wimg, br);
                writeA_lds(tid, sm16, fA);
                writeB_lds(tid, sm16 + 16384, br);
            }
            __syncthreads();

            int cur = 0;
            for (int it = 0; it < KIT; ++it) {
                float fA[16]; uint4 br[4];
                bool hn = (it + 1) < KIT;
                if (hn) {
                    loadA_regs(it + 1, tid, s_node, s_par, inputs, hOut, fA);
                    loadB_regs(it + 1, ntile, tid, Wimg, br);
                }
                mfma_phase(sm16 + cur * 8192, sm16 + 16384 + cur * 8192, wr, wc, lane, acc);
                if (hn) {
                    writeA_lds(tid, sm16 + (cur ^ 1) * 8192, fA);
                    writeB_lds(tid, sm16 + 16384 + (cur ^ 1) * 8192, br);
                }
                __syncthreads();
                cur ^= 1;
            }

            // epilogue: LDS transpose of acc + LSTM cell, 2 column-half passes
            float* eps = (float*)sm16;
            int cntloc = cnt - r0; if (cntloc > BM) cntloc = BM;
            int l15 = lane & 15, g = lane >> 4;
#pragma unroll
            for (int pass = 0; pass < 2; ++pass) {
                if (wc == pass) {
#pragma unroll
                    for (int m = 0; m < 4; ++m)
#pragma unroll
                        for (int n = 0; n < 4; ++n) {
                            int row = wr * 64 + m * 16 + g * 4;
                            int c = n * 16 + l15;
#pragma unroll
                            for (int r = 0; r < 4; ++r) eps[(row + r) * 68 + c] = acc[m][n][r];
                        }
                }
                __syncthreads();
#pragma unroll
                for (int e = 0; e < 4; ++e) {
                    int task = e * 256 + tid;
                    int row = task >> 3, dl = task & 7;
                    if (row < cntloc) {
                        int node = s_node[row]; int p = s_par[row];
                        const float* ep = &eps[row * 68 + dl * 8];
                        float4 v0 = *(const float4*)ep;
                        float4 v1 = *(const float4*)(ep + 4);
                        int jb = jc + pass * 64 + dl * 8;
                        float4 b0 = *(const float4*)(bias + jb);
                        float4 b1 = *(const float4*)(bias + jb + 4);
                        int d = jb >> 3;
                        float cp = (p > 0) ? cOut[(size_t)(p - 1) * DIM + d] : 0.f;
                        float cv = sigm(v0.x + b0.x) * tanh_fast(v0.z + b0.z) + sigm(v0.w + b0.w) * cp;
                        float hv = sigm(v0.y + b0.y) * tanh_fast(cv);
                        float cl = sigm(v1.x + b1.x) * tanh_fast(v1.z + b1.z) + sigm(v1.w + b1.w) * cp;
                        float hl = sigm(v1.y + b1.y) * tanh_fast(cl);
                        float tm0 = s_tm[row][0], tm1 = s_tm[row][1];
                        cOut[(size_t)node * DIM + d] = tm0 * cl + tm1 * cv;
                        hOut[(size_t)node * DIM + d] = tm0 * hl + tm1 * hv;
                    }
                }
                __syncthreads();
            }
        }
        grid.sync();
    }
}

// ---------------------------------------------------------------------------
extern "C" void kernel_launch(void* const* d_in, const int* in_sizes, int n_in,
                              void* d_out, int out_size, void* d_ws, size_t ws_size,
                              hipStream_t stream) {
    const float* inputs      = (const float*)d_in[0];
    const float* type_mask   = (const float*)d_in[1];
    const int*   parent      = (const int*)d_in[2];
    const float* W_ioux_vis  = (const float*)d_in[3];
    const float* b_ioux_vis  = (const float*)d_in[4];
    const float* W_iouh_vis  = (const float*)d_in[5];
    const float* b_iouh_vis  = (const float*)d_in[6];
    const float* W_fx_vis    = (const float*)d_in[7];
    const float* b_fx_vis    = (const float*)d_in[8];
    const float* W_fh_vis    = (const float*)d_in[9];
    const float* b_fh_vis    = (const float*)d_in[10];
    const float* W_ioux_lang = (const float*)d_in[11];
    const float* b_ioux_lang = (const float*)d_in[12];
    const float* W_iouh_lang = (const float*)d_in[13];
    const float* b_iouh_lang = (const float*)d_in[14];
    const float* W_fx_lang   = (const float*)d_in[15];
    const float* b_fx_lang   = (const float*)d_in[16];
    const float* W_fh_lang   = (const float*)d_in[17];
    const float* b_fh_lang   = (const float*)d_in[18];

    ushort_t* Wimg = (ushort_t*)d_ws;
    float* bias    = (float*)(Wimg + WIMG_USHORTS);
    int* order     = (int*)(bias + NCOLS);
    int* offsets   = order + N_NODES;
    int* counts    = offsets + (N_NODES + 1);
    int* cursors   = counts + (N_NODES + 1);
    int* nlev      = cursors + (N_NODES + 1);

    float* out = (float*)d_out;

    hipLaunchKernelGGL(prep_wimg_kernel, dim3(NTILE * KIT), dim3(256), 0, stream,
                       W_ioux_vis, W_iouh_vis, W_fx_vis, W_fh_vis,
                       W_ioux_lang, W_iouh_lang, W_fx_lang, W_fh_lang, Wimg);
    hipLaunchKernelGGL(prep_bias_kernel, dim3(NCOLS / 256), dim3(256), 0, stream,
                       b_ioux_vis, b_iouh_vis, b_fx_vis, b_fh_vis,
                       b_ioux_lang, b_iouh_lang, b_fx_lang, b_fh_lang, bias);
    hipLaunchKernelGGL(levels_sort_kernel, dim3(1), dim3(1024), 0, stream,
                       parent, order, offsets, counts, cursors, nlev);

    int occ = 0;
    if (hipOccupancyMaxActiveBlocksPerMultiprocessor(&occ, (const void*)tree_mfma_kernel, 256, 0) != hipSuccess || occ < 1)
        occ = 1;
    int bpc = occ < 2 ? occ : 2;
    dim3 grid(256 * bpc);

    void* args[] = { (void*)&inputs, (void*)&type_mask, (void*)&Wimg, (void*)&bias,
                     (void*)&order, (void*)&offsets, (void*)&nlev, (void*)&parent, (void*)&out };
    hipLaunchCooperativeKernel((const void*)tree_mfma_kernel, grid, dim3(256), args, 0, stream);
}

// Round 3
// 974.874 us; speedup vs baseline: 3.1094x; 1.5211x over previous
//
#include <hip/hip_runtime.h>
#include <math.h>

typedef unsigned short ushort_t;
typedef unsigned int uint_t;
typedef __attribute__((ext_vector_type(8))) short short8;
typedef __attribute__((ext_vector_type(4))) float f32x4;

#define N_NODES 8192
#define DIM 512
#define KTOT 1024
#define NCOLS 4096
#define BM 128
#define BN 128
#define BK 32
#define NTILE (NCOLS / BN)   // 32 column tiles
#define KIT (KTOT / BK)      // 32 k iterations
#define WIMG_USHORTS ((size_t)NTILE * KIT * 8192)
#define MAXLEV_LDS 512

__device__ __forceinline__ float sigm(float x) { return 1.0f / (1.0f + __expf(-x)); }
__device__ __forceinline__ float tanh_fast(float x) {
    float ax = fabsf(x);
    float e = __expf(2.0f * ax);
    float t = 1.0f - 2.0f / (e + 1.0f);
    return copysignf(t, x);
}

// ---------------------------------------------------------------------------
// Prep: weights -> split bf16 (hi+lo) LDS-image layout. (unchanged, verified)
// ---------------------------------------------------------------------------
__global__ void __launch_bounds__(256) prep_wimg_kernel(
    const float* __restrict__ Wx_iou_v, const float* __restrict__ Wh_iou_v,
    const float* __restrict__ Wx_f_v,   const float* __restrict__ Wh_f_v,
    const float* __restrict__ Wx_iou_l, const float* __restrict__ Wh_iou_l,
    const float* __restrict__ Wx_f_l,   const float* __restrict__ Wh_f_l,
    ushort_t* __restrict__ Wimg)
{
    __shared__ float T[32][132];   // T[kk][jloc]
    int p = blockIdx.x >> 5, it = blockIdx.x & 31;
    int tid = threadIdx.x;
#pragma unroll
    for (int e = 0; e < 16; ++e) {
        int lin = e * 256 + tid;
        int dloc = lin & 15, kk = (lin >> 4) & 31, q = lin >> 9;
        int d = p * 16 + dloc;
        int qq = q & 3; bool lang = q >= 4;
        int k = it * 32 + kk;
        const float* W; int col, stride;
        if (qq < 3) { col = qq * DIM + d; stride = 3 * DIM;
            W = (k < DIM) ? (lang ? Wx_iou_l : Wx_iou_v) : (lang ? Wh_iou_l : Wh_iou_v); }
        else        { col = d; stride = DIM;
            W = (k < DIM) ? (lang ? Wx_f_l : Wx_f_v) : (lang ? Wh_f_l : Wh_f_v); }
        int kr = (k < DIM) ? k : (k - DIM);
        T[kk][dloc * 8 + q] = W[(size_t)kr * stride + col];
    }
    __syncthreads();
    size_t tilebase = (size_t)blockIdx.x * 8192;
#pragma unroll
    for (int gch = 0; gch < 4; ++gch) {
        int gi = gch * 256 + tid;
        int plane = gi >> 9, col = (gi >> 2) & 127, gp = gi & 3;
        int gd = gp ^ (col & 3);
        uint_t wds[4];
#pragma unroll
        for (int i = 0; i < 4; ++i) {
            float f0 = T[gd * 8 + 2 * i][col];
            float f1 = T[gd * 8 + 2 * i + 1][col];
            uint_t u0 = __float_as_uint(f0), u1 = __float_as_uint(f1);
            uint_t h0 = u0 & 0xffff0000u, h1 = u1 & 0xffff0000u;
            uint_t v0, v1;
            if (plane == 0) { v0 = h0 >> 16; v1 = h1; }
            else {
                float r0 = f0 - __uint_as_float(h0), r1 = f1 - __uint_as_float(h1);
                v0 = __float_as_uint(r0) >> 16; v1 = __float_as_uint(r1) & 0xffff0000u;
            }
            wds[i] = v1 | v0;
        }
        *(uint4*)(Wimg + tilebase + (size_t)gi * 8) = make_uint4(wds[0], wds[1], wds[2], wds[3]);
    }
}

__global__ void prep_bias_kernel(
    const float* __restrict__ bx_iou_v, const float* __restrict__ bh_iou_v,
    const float* __restrict__ bx_f_v,   const float* __restrict__ bh_f_v,
    const float* __restrict__ bx_iou_l, const float* __restrict__ bh_iou_l,
    const float* __restrict__ bx_f_l,   const float* __restrict__ bh_f_l,
    float* __restrict__ bias)
{
    int j = blockIdx.x * blockDim.x + threadIdx.x;
    if (j >= NCOLS) return;
    int d = j >> 3, q = j & 7;
    int qq = q & 3;
    bool lang = (q & 4) != 0;
    const float* bx; const float* bh; int col;
    if (qq < 3) { col = qq * DIM + d; bx = lang ? bx_iou_l : bx_iou_v; bh = lang ? bh_iou_l : bh_iou_v; }
    else        { col = d;            bx = lang ? bx_f_l  : bx_f_v;   bh = lang ? bh_f_l  : bh_f_v; }
    bias[j] = bx[col] + bh[col];
}

// ---------------------------------------------------------------------------
// Level computation + counting sort + per-level tile table
// ---------------------------------------------------------------------------
__global__ void __launch_bounds__(1024) levels_sort_kernel(
    const int* __restrict__ parent,
    int* __restrict__ order, int* __restrict__ offsets,
    int* __restrict__ counts, int* __restrict__ cursors,
    int* __restrict__ nlev, int* __restrict__ tilestart)
{
    __shared__ int s_level[N_NODES];
    __shared__ int s_assigned;
    __shared__ int s_maxlev;
    int tid = threadIdx.x;
    int pr[8];
#pragma unroll
    for (int ii = 0; ii < 8; ++ii) {
        int i = tid + ii * 1024;
        pr[ii] = parent[i];
        s_level[i] = -1;
    }
    for (int i = tid; i <= N_NODES; i += 1024) counts[i] = 0;
    if (tid == 0) { s_assigned = 0; s_maxlev = 0; }
    __syncthreads();

    for (int pass = 0; pass <= N_NODES; ++pass) {
        int newly = 0;
#pragma unroll
        for (int ii = 0; ii < 8; ++ii) {
            int i = tid + ii * 1024;
            if (s_level[i] < 0) {
                int p = pr[ii];
                if (p == 0) { s_level[i] = 0; newly++; }
                else { int lp = s_level[p - 1]; if (lp >= 0) { s_level[i] = lp + 1; newly++; } }
            }
        }
        if (newly) atomicAdd(&s_assigned, newly);
        __syncthreads();
        int a = s_assigned;
        if (a >= N_NODES) break;
        __syncthreads();
    }

#pragma unroll
    for (int ii = 0; ii < 8; ++ii) {
        int i = tid + ii * 1024;
        int lv = s_level[i];
        atomicAdd(&counts[lv], 1);
        atomicMax(&s_maxlev, lv);
    }
    __syncthreads();
    if (tid == 0) {
        int nl = s_maxlev + 1;
        nlev[0] = nl;
        int off = 0, toff = 0;
        for (int l = 0; l < nl; ++l) {
            offsets[l] = off; cursors[l] = off; tilestart[l] = toff;
            toff += ((counts[l] + BM - 1) / BM) * NTILE;
            off += counts[l];
        }
        offsets[nl] = off;
        tilestart[nl] = toff;
        nlev[1] = toff;   // total tiles
    }
    __syncthreads();
#pragma unroll
    for (int ii = 0; ii < 8; ++ii) {
        int i = tid + ii * 1024;
        int pos = atomicAdd(&cursors[s_level[i]], 1);
        order[pos] = i;
    }
}

// ---------------------------------------------------------------------------
// Staging helpers (unchanged, verified round 2)
// ---------------------------------------------------------------------------
__device__ __forceinline__ void loadA_regs(int it, int tid,
    const int* s_node, const int* s_par,
    const float* __restrict__ inputs, const float* __restrict__ hOut, float* f)
{
    int row = tid >> 1, h16 = tid & 1;
    int node = s_node[row], p = s_par[row];
    bool xside = it < 16;
    bool valid = (node >= 0) && (xside || p > 0);
#pragma unroll
    for (int i = 0; i < 16; ++i) f[i] = 0.f;
    if (valid) {
        const float* base = xside ? (inputs + (size_t)node * DIM + it * 32 + h16 * 16)
                                  : (hOut + (size_t)(p - 1) * DIM + (it - 16) * 32 + h16 * 16);
#pragma unroll
        for (int q4 = 0; q4 < 4; ++q4) {
            float4 v = *(const float4*)(base + q4 * 4);
            f[q4 * 4 + 0] = v.x; f[q4 * 4 + 1] = v.y; f[q4 * 4 + 2] = v.z; f[q4 * 4 + 3] = v.w;
        }
    }
}

__device__ __forceinline__ void writeA_lds(int tid, ushort_t* Ab, const float* f)
{
    int row = tid >> 1, h16 = tid & 1;
    uint_t hw[8], lw[8];
#pragma unroll
    for (int i = 0; i < 8; ++i) {
        float f0 = f[2 * i], f1 = f[2 * i + 1];
        uint_t u0 = __float_as_uint(f0), u1 = __float_as_uint(f1);
        uint_t h0 = u0 & 0xffff0000u, h1 = u1 & 0xffff0000u;
        float r0 = f0 - __uint_as_float(h0), r1 = f1 - __uint_as_float(h1);
        hw[i] = h1 | (h0 >> 16);
        lw[i] = (__float_as_uint(r1) & 0xffff0000u) | (__float_as_uint(r0) >> 16);
    }
    int gd0 = h16 * 2, gd1 = gd0 + 1, rs = row & 3;
    ushort_t* base = Ab + row * 32;
    *(uint4*)(base + (gd0 ^ rs) * 8)        = make_uint4(hw[0], hw[1], hw[2], hw[3]);
    *(uint4*)(base + (gd1 ^ rs) * 8)        = make_uint4(hw[4], hw[5], hw[6], hw[7]);
    *(uint4*)(base + 4096 + (gd0 ^ rs) * 8) = make_uint4(lw[0], lw[1], lw[2], lw[3]);
    *(uint4*)(base + 4096 + (gd1 ^ rs) * 8) = make_uint4(lw[4], lw[5], lw[6], lw[7]);
}

__device__ __forceinline__ void loadB_regs(int it, int ntile, int tid,
                                           const ushort_t* __restrict__ Wimg, uint4* br)
{
    const uint4* g = (const uint4*)(Wimg + ((size_t)(ntile * KIT + it)) * 8192);
#pragma unroll
    for (int j = 0; j < 4; ++j) br[j] = g[(size_t)tid + 256 * j];
}

__device__ __forceinline__ void writeB_lds(int tid, ushort_t* Bb, const uint4* br)
{
    uint4* d = (uint4*)Bb;
#pragma unroll
    for (int j = 0; j < 4; ++j) d[tid + 256 * j] = br[j];
}

__device__ __forceinline__ void mfma_phase(const ushort_t* Ab, const ushort_t* Bb,
                                           int wr, int wc, int lane, f32x4 acc[4][4])
{
    int l15 = lane & 15, g = lane >> 4;
    short8 ah[4], al[4];
#pragma unroll
    for (int m = 0; m < 4; ++m) {
        int row = wr * 64 + m * 16 + l15;
        const ushort_t* pa = Ab + row * 32 + ((g ^ (row & 3)) * 8);
        ah[m] = *(const short8*)pa;
        al[m] = *(const short8*)(pa + 4096);
    }
#pragma unroll
    for (int n = 0; n < 4; ++n) {
        int col = wc * 64 + n * 16 + l15;
        const ushort_t* pb = Bb + col * 32 + ((g ^ (col & 3)) * 8);
        short8 bh = *(const short8*)pb;
        short8 bl = *(const short8*)(pb + 4096);
#pragma unroll
        for (int m = 0; m < 4; ++m) {
            acc[m][n] = __builtin_amdgcn_mfma_f32_16x16x32_bf16(ah[m], bh, acc[m][n], 0, 0, 0);
            acc[m][n] = __builtin_amdgcn_mfma_f32_16x16x32_bf16(al[m], bh, acc[m][n], 0, 0, 0);
            acc[m][n] = __builtin_amdgcn_mfma_f32_16x16x32_bf16(ah[m], bl, acc[m][n], 0, 0, 0);
        }
    }
}

// ---------------------------------------------------------------------------
// Dataflow worker: persistent blocks, in-order strided tile list, per-node
// readiness counters (fan-in 32), NO grid-wide barriers.
// ---------------------------------------------------------------------------
__global__ void __launch_bounds__(256, 2) tree_dataflow_kernel(
    const float* __restrict__ inputs, const float* __restrict__ type_mask,
    const ushort_t* __restrict__ Wimg, const float* __restrict__ bias,
    const int* __restrict__ order, const int* __restrict__ offsets,
    const int* __restrict__ nlev, const int* __restrict__ parent,
    const int* __restrict__ tilestart, int* __restrict__ readyCnt,
    float* __restrict__ out)
{
    float* cOut = out;
    float* hOut = out + (size_t)N_NODES * DIM;

    __shared__ __align__(16) ushort_t sm16[32768];   // 64KB staging/epilogue
    __shared__ int s_node[BM];
    __shared__ int s_par[BM];
    __shared__ float s_tm[BM][2];
    __shared__ int s_ts[MAXLEV_LDS];
    __shared__ int s_off[MAXLEV_LDS];

    int tid = threadIdx.x;
    int lane = tid & 63, w = tid >> 6, wr = w >> 1, wc = w & 1;
    int nl = nlev[0];
    int total = nlev[1];

    int nload = nl + 1; if (nload > MAXLEV_LDS) nload = MAXLEV_LDS;
    for (int i = tid; i < nload; i += 256) { s_ts[i] = tilestart[i]; s_off[i] = offsets[i]; }
    __syncthreads();

    for (int t = blockIdx.x; t < total; t += gridDim.x) {
        int lev = 0;
        while (lev + 1 < nload && s_ts[lev + 1] <= t) ++lev;
        int lt = t - s_ts[lev];
        int ntile = lt % NTILE;
        int mt = lt / NTILE;
        int start = s_off[lev];
        int cnt = s_off[lev + 1] - start;
        int jc = ntile * BN;
        int r0 = mt * BM;

        if (tid < BM) {
            int r = r0 + tid;
            int node = (r < cnt) ? order[start + r] : -1;
            s_node[tid] = node;
            int p = (node >= 0) ? parent[node] : 0;
            s_par[tid] = p;
            float t0 = 0.f, t1 = 0.f;
            if (node >= 0) { t0 = type_mask[node * 2]; t1 = type_mask[node * 2 + 1]; }
            s_tm[tid][0] = t0; s_tm[tid][1] = t1;
        }
        __syncthreads();

        f32x4 acc[4][4];
#pragma unroll
        for (int m = 0; m < 4; ++m)
#pragma unroll
            for (int n = 0; n < 4; ++n) acc[m][n] = (f32x4)(0.f);

        // ---- x-side half (K 0..511): depends only on inputs, always ready
        {
            float fA[16]; uint4 br[4];
            loadA_regs(0, tid, s_node, s_par, inputs, hOut, fA);
            loadB_regs(0, ntile, tid, Wimg, br);
            writeA_lds(tid, sm16, fA);
            writeB_lds(tid, sm16 + 16384, br);
        }
        __syncthreads();
        int cur = 0;
        for (int it = 0; it < 16; ++it) {
            float fA[16]; uint4 br[4];
            bool hn = it < 15;
            if (hn) {
                loadA_regs(it + 1, tid, s_node, s_par, inputs, hOut, fA);
                loadB_regs(it + 1, ntile, tid, Wimg, br);
            }
            mfma_phase(sm16 + cur * 8192, sm16 + 16384 + cur * 8192, wr, wc, lane, acc);
            if (hn) {
                writeA_lds(tid, sm16 + (cur ^ 1) * 8192, fA);
                writeB_lds(tid, sm16 + 16384 + (cur ^ 1) * 8192, br);
            }
            __syncthreads();
            cur ^= 1;
        }

        // ---- wait for parents (fan-in 32 column tiles each)
        if (tid < BM) {
            int node = s_node[tid], p = s_par[tid];
            if (node >= 0 && p > 0) {
                while (__hip_atomic_load(&readyCnt[p - 1], __ATOMIC_RELAXED,
                                         __HIP_MEMORY_SCOPE_AGENT) < NTILE)
                    __builtin_amdgcn_s_sleep(2);
            }
        }
        __syncthreads();
        if (lev > 0)
            __builtin_amdgcn_fence(__ATOMIC_ACQUIRE, "agent");

        // ---- h-side half (K 512..1023): gathers parent h rows
        {
            float fA[16]; uint4 br[4];
            loadA_regs(16, tid, s_node, s_par, inputs, hOut, fA);
            loadB_regs(16, ntile, tid, Wimg, br);
            writeA_lds(tid, sm16, fA);
            writeB_lds(tid, sm16 + 16384, br);
        }
        __syncthreads();
        cur = 0;
        for (int it = 16; it < 32; ++it) {
            float fA[16]; uint4 br[4];
            bool hn = it < 31;
            if (hn) {
                loadA_regs(it + 1, tid, s_node, s_par, inputs, hOut, fA);
                loadB_regs(it + 1, ntile, tid, Wimg, br);
            }
            mfma_phase(sm16 + cur * 8192, sm16 + 16384 + cur * 8192, wr, wc, lane, acc);
            if (hn) {
                writeA_lds(tid, sm16 + (cur ^ 1) * 8192, fA);
                writeB_lds(tid, sm16 + 16384 + (cur ^ 1) * 8192, br);
            }
            __syncthreads();
            cur ^= 1;
        }

        // ---- epilogue: acc transpose in LDS + LSTM cell, 2 column-half passes
        float* eps = (float*)sm16;
        int cntloc = cnt - r0; if (cntloc > BM) cntloc = BM;
        int l15 = lane & 15, g = lane >> 4;
#pragma unroll
        for (int pass = 0; pass < 2; ++pass) {
            if (wc == pass) {
#pragma unroll
                for (int m = 0; m < 4; ++m)
#pragma unroll
                    for (int n = 0; n < 4; ++n) {
                        int row = wr * 64 + m * 16 + g * 4;
                        int c = n * 16 + l15;
#pragma unroll
                        for (int r = 0; r < 4; ++r) eps[(row + r) * 68 + c] = acc[m][n][r];
                    }
            }
            __syncthreads();
#pragma unroll
            for (int e = 0; e < 4; ++e) {
                int task = e * 256 + tid;
                int row = task >> 3, dl = task & 7;
                if (row < cntloc) {
                    int node = s_node[row]; int p = s_par[row];
                    const float* ep = &eps[row * 68 + dl * 8];
                    float4 v0 = *(const float4*)ep;
                    float4 v1 = *(const float4*)(ep + 4);
                    int jb = jc + pass * 64 + dl * 8;
                    float4 b0 = *(const float4*)(bias + jb);
                    float4 b1 = *(const float4*)(bias + jb + 4);
                    int d = jb >> 3;
                    float cp = (p > 0) ? cOut[(size_t)(p - 1) * DIM + d] : 0.f;
                    float cv = sigm(v0.x + b0.x) * tanh_fast(v0.z + b0.z) + sigm(v0.w + b0.w) * cp;
                    float hv = sigm(v0.y + b0.y) * tanh_fast(cv);
                    float cl = sigm(v1.x + b1.x) * tanh_fast(v1.z + b1.z) + sigm(v1.w + b1.w) * cp;
                    float hl = sigm(v1.y + b1.y) * tanh_fast(cl);
                    float tm0 = s_tm[row][0], tm1 = s_tm[row][1];
                    cOut[(size_t)node * DIM + d] = tm0 * cl + tm1 * cv;
                    hOut[(size_t)node * DIM + d] = tm0 * hl + tm1 * hv;
                }
            }
            __syncthreads();
        }

        // ---- publish: release-RMW per finished row (wbL2 + flag increment)
        if (tid < BM) {
            int node = s_node[tid];
            if (node >= 0)
                __hip_atomic_fetch_add(&readyCnt[node], 1, __ATOMIC_RELEASE,
                                       __HIP_MEMORY_SCOPE_AGENT);
        }
        // next tile's s_node write is by the same tid<128 threads; others
        // only touch LDS after the following top-of-loop __syncthreads
    }
}

// ---------------------------------------------------------------------------
extern "C" void kernel_launch(void* const* d_in, const int* in_sizes, int n_in,
                              void* d_out, int out_size, void* d_ws, size_t ws_size,
                              hipStream_t stream) {
    const float* inputs      = (const float*)d_in[0];
    const float* type_mask   = (const float*)d_in[1];
    const int*   parent      = (const int*)d_in[2];
    const float* W_ioux_vis  = (const float*)d_in[3];
    const float* b_ioux_vis  = (const float*)d_in[4];
    const float* W_iouh_vis  = (const float*)d_in[5];
    const float* b_iouh_vis  = (const float*)d_in[6];
    const float* W_fx_vis    = (const float*)d_in[7];
    const float* b_fx_vis    = (const float*)d_in[8];
    const float* W_fh_vis    = (const float*)d_in[9];
    const float* b_fh_vis    = (const float*)d_in[10];
    const float* W_ioux_lang = (const float*)d_in[11];
    const float* b_ioux_lang = (const float*)d_in[12];
    const float* W_iouh_lang = (const float*)d_in[13];
    const float* b_iouh_lang = (const float*)d_in[14];
    const float* W_fx_lang   = (const float*)d_in[15];
    const float* b_fx_lang   = (const float*)d_in[16];
    const float* W_fh_lang   = (const float*)d_in[17];
    const float* b_fh_lang   = (const float*)d_in[18];

    ushort_t* Wimg = (ushort_t*)d_ws;
    float* bias    = (float*)(Wimg + WIMG_USHORTS);
    int* order     = (int*)(bias + NCOLS);
    int* offsets   = order + N_NODES;
    int* counts    = offsets + (N_NODES + 2);
    int* cursors   = counts + (N_NODES + 2);
    int* nlev      = cursors + (N_NODES + 2);
    int* tilestart = nlev + 8;
    int* readyCnt  = tilestart + (N_NODES + 2);

    float* out = (float*)d_out;

    hipMemsetAsync((void*)readyCnt, 0, N_NODES * sizeof(int), stream);

    hipLaunchKernelGGL(prep_wimg_kernel, dim3(NTILE * KIT), dim3(256), 0, stream,
                       W_ioux_vis, W_iouh_vis, W_fx_vis, W_fh_vis,
                       W_ioux_lang, W_iouh_lang, W_fx_lang, W_fh_lang, Wimg);
    hipLaunchKernelGGL(prep_bias_kernel, dim3(NCOLS / 256), dim3(256), 0, stream,
                       b_ioux_vis, b_iouh_vis, b_fx_vis, b_fh_vis,
                       b_ioux_lang, b_iouh_lang, b_fx_lang, b_fh_lang, bias);
    hipLaunchKernelGGL(levels_sort_kernel, dim3(1), dim3(1024), 0, stream,
                       parent, order, offsets, counts, cursors, nlev, tilestart);

    int occ = 0;
    if (hipOccupancyMaxActiveBlocksPerMultiprocessor(&occ, (const void*)tree_dataflow_kernel, 256, 0) != hipSuccess || occ < 1)
        occ = 1;
    int bpc = occ < 2 ? occ : 2;
    dim3 grid(256 * bpc);

    void* args[] = { (void*)&inputs, (void*)&type_mask, (void*)&Wimg, (void*)&bias,
                     (void*)&order, (void*)&offsets, (void*)&nlev, (void*)&parent,
                     (void*)&tilestart, (void*)&readyCnt, (void*)&out };
    hipLaunchCooperativeKernel((const void*)tree_dataflow_kernel, grid, dim3(256), args, 0, stream);
}